// Round 7
// baseline (1462.095 us; speedup 1.0000x reference)
//
#include <hip/hip_runtime.h>
#include <hip/hip_bf16.h>

using bf16 = __hip_bfloat16;
typedef short  short8  __attribute__((ext_vector_type(8)));   // 8 bf16
typedef float  f32x4   __attribute__((ext_vector_type(4)));
typedef float  f32x16  __attribute__((ext_vector_type(16)));
typedef unsigned short us4 __attribute__((ext_vector_type(4)));

static __device__ __forceinline__ float b2f(bf16 v) { return __bfloat162float(v); }
static __device__ __forceinline__ bf16  f2b(float v) { return __float2bfloat16(v); }
static __device__ __forceinline__ unsigned short f2bu(float v) {
    bf16 t = __float2bfloat16(v);
    return *(unsigned short*)&t;
}

// ---------------------------------------------------------------------------
// Pack binarized OIHW weights into 32x32x16 MFMA A-fragment order:
// frag f = (mt*9 + r)*(IC/16) + cc ; lane l holds oc = mt*32+(l&31),
// k-slice ic = cc*16 + (l>>5)*8 + j.
__device__ __forceinline__ void pack32_one(const float* __restrict__ w,
                                           bf16* __restrict__ o, int i, int IC) {
    int j = i & 7;
    int l = (i >> 3) & 63;
    int f = i >> 9;
    int ICD16 = IC >> 4;
    int cc = f % ICD16;
    int t  = f / ICD16;
    int r  = t % 9;
    int mt = t / 9;
    int oc = mt * 32 + (l & 31);
    int ic = cc * 16 + ((l >> 5) << 3) + j;
    o[i] = f2b((w[(oc * IC + ic) * 9 + r] >= 0.f) ? 1.f : -1.f);
}

// One merged binarize/pack kernel (saves 3 launches).
__global__ __launch_bounds__(256) void binpack_kernel(
    const float* __restrict__ w1, const float* __restrict__ w2,
    const float* __restrict__ w3, const float* __restrict__ w4,
    float* __restrict__ w1t, bf16* __restrict__ wA2,
    bf16* __restrict__ wA3, float* __restrict__ wc4) {
    int i = blockIdx.x * 256 + threadIdx.x;
    if (i < 73728) {
        pack32_one(w2, wA2, i, 128);
    } else if (i < 73728 + 18432) {
        pack32_one(w3, wA3, i - 73728, 64);
    } else if (i < 73728 + 18432 + 1152) {
        int k = i - (73728 + 18432);           // w1 [128][9] -> w1t [9][128]
        int c = k / 9, r = k % 9;
        w1t[r * 128 + c] = (w1[k] >= 0.f) ? 1.f : -1.f;
    } else if (i < 73728 + 18432 + 1152 + 1536) {
        int k = i - (73728 + 18432 + 1152);    // w4 [8][32][6] -> wc4 [8][6][32]
        int oc = k / 192, rem = k % 192;
        int ic = rem / 6, r = rem % 6;
        wc4[oc * 192 + r * 32 + ic] = (w4[k] >= 0.f) ? 1.f : -1.f;
    }
}

// ---------------------------------------------------------------------------
// conv1 (1->128) + bias + leaky + pool.  x f32 NCHW -> a1 bf16 NHWC.
// 256 thr = 128 c x 2 groups; each thread computes 4 pooled px of one row.
// x loads vectorized f32x4 (wave-uniform edge guard).
// ---------------------------------------------------------------------------
__global__ __launch_bounds__(256) void conv1_kernel(
    const float* __restrict__ x, const float* __restrict__ w1t,
    const float* __restrict__ b1, bf16* __restrict__ a1) {
    const int tid = threadIdx.x;
    const int c = tid & 127;
    const int b = blockIdx.y;
    int idx = blockIdx.x * 2 + (tid >> 7);
    if (idx >= 111 * 28) return;
    int ph = idx / 28, pwg = idx % 28;
    int pw0 = pwg * 4;

    float s[9];
#pragma unroll
    for (int k = 0; k < 9; ++k) s[k] = w1t[k * 128 + c];
    const float bias = b1[c];

    const float* xp = x + (size_t)b * 224 * 224 + (2 * ph) * 224 + 2 * pw0;
    const bool full = (pwg < 27);  // wave-uniform (idx uniform per 128 threads)
    float win[4][12];
#pragma unroll
    for (int r = 0; r < 4; ++r) {
        f32x4 v0 = *(const f32x4*)(xp + r * 224);
        f32x4 v1 = *(const f32x4*)(xp + r * 224 + 4);
        f32x4 v2 = full ? *(const f32x4*)(xp + r * 224 + 8) : (f32x4){0.f, 0.f, 0.f, 0.f};
#pragma unroll
        for (int j = 0; j < 4; ++j) {
            win[r][j] = v0[j];
            win[r][4 + j] = v1[j];
            win[r][8 + j] = v2[j];
        }
    }

#pragma unroll
    for (int p = 0; p < 4; ++p) {
        int pw = pw0 + p;
        if (pw < 111) {
            float m = -1e30f;
#pragma unroll
            for (int i = 0; i < 2; ++i)
#pragma unroll
                for (int jj = 0; jj < 2; ++jj) {
                    float acc = bias;
#pragma unroll
                    for (int kh = 0; kh < 3; ++kh)
#pragma unroll
                        for (int kw = 0; kw < 3; ++kw)
                            acc += s[kh * 3 + kw] * win[i + kh][2 * p + jj + kw];
                    acc = (acc >= 0.f) ? acc : 0.5f * acc;
                    m = fmaxf(m, acc);
                }
            a1[((size_t)(b * 111 + ph) * 111 + pw) * 128 + c] = f2b(m);
        }
    }
}

// ---------------------------------------------------------------------------
// MFMA 32x32x16 implicit-GEMM conv3x3 + bias + leaky + maxpool2.
// Block: 256 thr, tile 16x16 conv px; wave w: rows 4w..4w+3 (2 n-tiles of
// 2 rows x 16 cols), all OC (MT m-tiles of 32). IC chunked by 32 into LDS
// (20.7 KB -> 6 blocks/CU with VGPR<=85).
// ---------------------------------------------------------------------------
template <int IC, int OC, int IN, int POOL>
__global__ __launch_bounds__(256, 6) void convmfma_kernel(
    const bf16* __restrict__ in, const bf16* __restrict__ wAp,
    const float* __restrict__ bias, bf16* __restrict__ out) {
    constexpr int MT = OC / 32;
    constexpr int CHUNKS = IC / 32;
    constexpr int ICD16 = IC / 16;
    __shared__ __align__(16) char smem[18 * 18 * 64];  // 20736 B

    const int tid = threadIdx.x;
    const int b = blockIdx.z;
    const int oh0 = blockIdx.y * 16;
    const int ow0 = blockIdx.x * 16;

    const int w   = tid >> 6;
    const int l   = tid & 63;
    const int lc4 = l & 15;
    const int r2  = (l >> 4) & 1;
    const int hh  = l >> 5;

    f32x16 acc[MT][2];
#pragma unroll
    for (int mt = 0; mt < MT; ++mt)
#pragma unroll
        for (int nt = 0; nt < 2; ++nt)
#pragma unroll
            for (int q = 0; q < 16; ++q) acc[mt][nt][q] = 0.f;

    for (int chunk = 0; chunk < CHUNKS; ++chunk) {
        if (chunk) __syncthreads();
        // ---- stage window rows oh0..+17, cols ow0..+17, ic chunk*32..+31 ----
        {
            const bf16* src = in + ((size_t)b * IN * IN) * IC + chunk * 32;
            for (int u = tid; u < 18 * 18 * 4; u += 256) {
                int slot = u & 3, cell = u >> 2;
                int row = cell / 18, col = cell - row * 18;
                int gr = oh0 + row, gc = ow0 + col;
                f32x4 v = {0.f, 0.f, 0.f, 0.f};
                if (gr < IN && gc < IN)
                    v = *(const f32x4*)(src + ((size_t)gr * IN + gc) * IC + slot * 8);
                *(f32x4*)(smem + cell * 64 + ((slot ^ ((col >> 1) & 3)) << 4)) = v;
            }
        }
        __syncthreads();

        // ---- K-loop: 9 taps x 2 ic-slices of 16 ----
#pragma unroll
        for (int kh = 0; kh < 3; ++kh) {
#pragma unroll
            for (int kw = 0; kw < 3; ++kw) {
                const int r = kh * 3 + kw;
                const int wincol = lc4 + kw;
                const int sx = (wincol >> 1) & 3;
#pragma unroll
                for (int cc = 0; cc < 2; ++cc) {
                    short8 af[MT];
#pragma unroll
                    for (int mt = 0; mt < MT; ++mt)
                        af[mt] = ((const short8*)wAp)[
                            (((mt * 9 + r) * ICD16) + chunk * 2 + cc) * 64 + l];
                    const int slot = cc * 2 + hh;
                    short8 bfr[2];
#pragma unroll
                    for (int nt = 0; nt < 2; ++nt) {
                        int cell = (4 * w + 2 * nt + r2 + kh) * 18 + wincol;
                        bfr[nt] = *(const short8*)(
                            smem + cell * 64 + ((slot ^ sx) << 4));
                    }
#pragma unroll
                    for (int mt = 0; mt < MT; ++mt)
#pragma unroll
                        for (int nt = 0; nt < 2; ++nt)
                            acc[mt][nt] = __builtin_amdgcn_mfma_f32_32x32x16_bf16(
                                af[mt], bfr[nt], acc[mt][nt], 0, 0, 0);
                }
            }
        }
    }

    // ---- epilogue: bias + leaky + 2x2 pool (rows at lane^16, cols lane^1) ----
    const bool wr = ((l & 17) == 0);
    const int pw = blockIdx.x * 8 + (lc4 >> 1);
#pragma unroll
    for (int mt = 0; mt < MT; ++mt) {
#pragma unroll
        for (int nt = 0; nt < 2; ++nt) {
            const int ph = blockIdx.y * 8 + 2 * w + nt;
#pragma unroll
            for (int g = 0; g < 4; ++g) {
                us4 o;
#pragma unroll
                for (int q2 = 0; q2 < 4; ++q2) {
                    int q = g * 4 + q2;
                    int oc = mt * 32 + 8 * g + 4 * hh + q2;
                    float v = acc[mt][nt][q] + bias[oc];
                    v = (v >= 0.f) ? v : 0.5f * v;
                    float m1 = fmaxf(v, __shfl_xor(v, 1));
                    float m  = fmaxf(m1, __shfl_xor(m1, 16));
                    o[q2] = f2bu(m);
                }
                if (wr && ph < POOL && pw < POOL)
                    *(us4*)(&out[((size_t)(b * POOL + ph) * POOL + pw) * OC +
                                 mt * 32 + 8 * g + 4 * hh]) = o;
            }
        }
    }
}

// ---------------------------------------------------------------------------
// conv4 (32->8, 3x2) + bias.  a3 NHWC bf16 -> out f32 [32][4800]
// ---------------------------------------------------------------------------
__global__ __launch_bounds__(256) void conv4_kernel(
    const bf16* __restrict__ a3, const float* __restrict__ wc4,
    const float* __restrict__ b4, float* __restrict__ out) {
    int i = blockIdx.x * 256 + threadIdx.x;
    if (i >= 32 * 4800) return;
    int b = i / 4800;
    int rem = i % 4800;
    int oc = rem / 600;
    int r2 = rem % 600;
    int oh = r2 / 25, ow = r2 % 25;

    float acc = b4[oc];
    int rr = 0;
#pragma unroll
    for (int kh = 0; kh < 3; ++kh) {
#pragma unroll
        for (int kw = 0; kw < 2; ++kw, ++rr) {
            const bf16* xp = a3 + ((size_t)(b * 26 + oh + kh) * 26 + (ow + kw)) * 32;
            const float* wp = wc4 + oc * 192 + rr * 32;
            short8 x0 = *(const short8*)(xp);
            short8 x1 = *(const short8*)(xp + 8);
            short8 x2 = *(const short8*)(xp + 16);
            short8 x3 = *(const short8*)(xp + 24);
#pragma unroll
            for (int j = 0; j < 8; ++j) {
                union { short s; unsigned short u; } u0{x0[j]}, u1{x1[j]}, u2{x2[j]}, u3{x3[j]};
                acc += wp[j]      * __bfloat162float(__hip_bfloat16_raw{u0.u});
                acc += wp[8 + j]  * __bfloat162float(__hip_bfloat16_raw{u1.u});
                acc += wp[16 + j] * __bfloat162float(__hip_bfloat16_raw{u2.u});
                acc += wp[24 + j] * __bfloat162float(__hip_bfloat16_raw{u3.u});
            }
        }
    }
    out[i] = acc;
}

// ---------------------------------------------------------------------------
extern "C" void kernel_launch(void* const* d_in, const int* in_sizes, int n_in,
                              void* d_out, int out_size, void* d_ws, size_t ws_size,
                              hipStream_t stream) {
    const float* x  = (const float*)d_in[0];
    const float* w1 = (const float*)d_in[1];
    const float* b1 = (const float*)d_in[2];
    const float* w2 = (const float*)d_in[3];
    const float* b2 = (const float*)d_in[4];
    const float* w3 = (const float*)d_in[5];
    const float* b3 = (const float*)d_in[6];
    const float* w4 = (const float*)d_in[7];
    const float* b4 = (const float*)d_in[8];
    float* out = (float*)d_out;

    char* ws = (char*)d_ws;
    size_t off = 0;
    auto alloc = [&](size_t bytes) {
        void* p = ws + off;
        off = (off + bytes + 255) & ~(size_t)255;
        return p;
    };
    bf16* a1 = (bf16*)alloc((size_t)32 * 111 * 111 * 128 * 2);  // NHWC
    bf16* a2 = (bf16*)alloc((size_t)32 * 54 * 54 * 64 * 2);     // NHWC
    bf16* a3 = (bf16*)alloc((size_t)32 * 26 * 26 * 32 * 2);     // NHWC
    float* w1t = (float*)alloc(1152 * 4);
    bf16* wAp2 = (bf16*)alloc(73728 * 2);
    bf16* wAp3 = (bf16*)alloc(18432 * 2);
    float* wc4 = (float*)alloc(1536 * 4);

    // binarize + pack all weights (one launch)
    binpack_kernel<<<dim3((94848 + 255) / 256), 256, 0, stream>>>(
        w1, w2, w3, w4, w1t, wAp2, wAp3, wc4);

    // conv1: x -> a1 [32,111,111,128]
    dim3 g1((111 * 28 + 1) / 2, 32);
    conv1_kernel<<<g1, 256, 0, stream>>>(x, w1t, b1, a1);

    // conv2: a1 -> a2 [32,54,54,64]  (conv extent 108x108)
    dim3 g2(7, 7, 32);
    convmfma_kernel<128, 64, 111, 54><<<g2, 256, 0, stream>>>(a1, wAp2, b2, a2);

    // conv3: a2 -> a3 [32,26,26,32]  (conv extent 52x52)
    dim3 g3(4, 4, 32);
    convmfma_kernel<64, 32, 54, 26><<<g3, 256, 0, stream>>>(a2, wAp3, b3, a3);

    // conv4: a3 -> out [32,4800]
    conv4_kernel<<<dim3((32 * 4800 + 255) / 256), 256, 0, stream>>>(
        a3, wc4, b4, out);
}

// Round 8
// 331.366 us; speedup vs baseline: 4.4123x; 4.4123x over previous
//
#include <hip/hip_runtime.h>
#include <hip/hip_bf16.h>

using bf16 = __hip_bfloat16;
typedef short  short8  __attribute__((ext_vector_type(8)));   // 8 bf16
typedef float  f32x4   __attribute__((ext_vector_type(4)));
typedef float  f32x16  __attribute__((ext_vector_type(16)));
typedef unsigned short us4 __attribute__((ext_vector_type(4)));

static __device__ __forceinline__ float b2f(bf16 v) { return __bfloat162float(v); }
static __device__ __forceinline__ bf16  f2b(float v) { return __float2bfloat16(v); }
static __device__ __forceinline__ unsigned short f2bu(float v) {
    bf16 t = __float2bfloat16(v);
    return *(unsigned short*)&t;
}

// ---------------------------------------------------------------------------
// Pack binarized OIHW weights into 32x32x16 MFMA A-fragment order:
// frag f = (mt*9 + r)*(IC/16) + cc ; lane l holds oc = mt*32+(l&31),
// k-slice ic = cc*16 + (l>>5)*8 + j.
__device__ __forceinline__ void pack32_one(const float* __restrict__ w,
                                           bf16* __restrict__ o, int i, int IC) {
    int j = i & 7;
    int l = (i >> 3) & 63;
    int f = i >> 9;
    int ICD16 = IC >> 4;
    int cc = f % ICD16;
    int t  = f / ICD16;
    int r  = t % 9;
    int mt = t / 9;
    int oc = mt * 32 + (l & 31);
    int ic = cc * 16 + ((l >> 5) << 3) + j;
    o[i] = f2b((w[(oc * IC + ic) * 9 + r] >= 0.f) ? 1.f : -1.f);
}

// One merged binarize/pack kernel (saves 3 launches).
__global__ __launch_bounds__(256) void binpack_kernel(
    const float* __restrict__ w1, const float* __restrict__ w2,
    const float* __restrict__ w3, const float* __restrict__ w4,
    float* __restrict__ w1t, bf16* __restrict__ wA2,
    bf16* __restrict__ wA3, float* __restrict__ wc4) {
    int i = blockIdx.x * 256 + threadIdx.x;
    if (i < 73728) {
        pack32_one(w2, wA2, i, 128);
    } else if (i < 73728 + 18432) {
        pack32_one(w3, wA3, i - 73728, 64);
    } else if (i < 73728 + 18432 + 1152) {
        int k = i - (73728 + 18432);           // w1 [128][9] -> w1t [9][128]
        int c = k / 9, r = k % 9;
        w1t[r * 128 + c] = (w1[k] >= 0.f) ? 1.f : -1.f;
    } else if (i < 73728 + 18432 + 1152 + 1536) {
        int k = i - (73728 + 18432 + 1152);    // w4 [8][32][6] -> wc4 [8][6][32]
        int oc = k / 192, rem = k % 192;
        int ic = rem / 6, r = rem % 6;
        wc4[oc * 192 + r * 32 + ic] = (w4[k] >= 0.f) ? 1.f : -1.f;
    }
}

// ---------------------------------------------------------------------------
// conv1 (1->128) + bias + leaky + pool.  x f32 NCHW -> a1 bf16 NHWC.
// 256 thr = 128 c x 2 groups; each thread computes 4 pooled px of one row.
// x loads vectorized f32x4 (wave-uniform edge guard).
// ---------------------------------------------------------------------------
__global__ __launch_bounds__(256) void conv1_kernel(
    const float* __restrict__ x, const float* __restrict__ w1t,
    const float* __restrict__ b1, bf16* __restrict__ a1) {
    const int tid = threadIdx.x;
    const int c = tid & 127;
    const int b = blockIdx.y;
    int idx = blockIdx.x * 2 + (tid >> 7);
    if (idx >= 111 * 28) return;
    int ph = idx / 28, pwg = idx % 28;
    int pw0 = pwg * 4;

    float s[9];
#pragma unroll
    for (int k = 0; k < 9; ++k) s[k] = w1t[k * 128 + c];
    const float bias = b1[c];

    const float* xp = x + (size_t)b * 224 * 224 + (2 * ph) * 224 + 2 * pw0;
    const bool full = (pwg < 27);  // wave-uniform (idx uniform per 128 threads)
    float win[4][12];
#pragma unroll
    for (int r = 0; r < 4; ++r) {
        f32x4 v0 = *(const f32x4*)(xp + r * 224);
        f32x4 v1 = *(const f32x4*)(xp + r * 224 + 4);
        f32x4 v2 = full ? *(const f32x4*)(xp + r * 224 + 8) : (f32x4){0.f, 0.f, 0.f, 0.f};
#pragma unroll
        for (int j = 0; j < 4; ++j) {
            win[r][j] = v0[j];
            win[r][4 + j] = v1[j];
            win[r][8 + j] = v2[j];
        }
    }

#pragma unroll
    for (int p = 0; p < 4; ++p) {
        int pw = pw0 + p;
        if (pw < 111) {
            float m = -1e30f;
#pragma unroll
            for (int i = 0; i < 2; ++i)
#pragma unroll
                for (int jj = 0; jj < 2; ++jj) {
                    float acc = bias;
#pragma unroll
                    for (int kh = 0; kh < 3; ++kh)
#pragma unroll
                        for (int kw = 0; kw < 3; ++kw)
                            acc += s[kh * 3 + kw] * win[i + kh][2 * p + jj + kw];
                    acc = (acc >= 0.f) ? acc : 0.5f * acc;
                    m = fmaxf(m, acc);
                }
            a1[((size_t)(b * 111 + ph) * 111 + pw) * 128 + c] = f2b(m);
        }
    }
}

// ---------------------------------------------------------------------------
// MFMA 32x32x16 implicit-GEMM conv3x3 + bias + leaky + maxpool2.
// Block: 256 thr, tile 16x16 conv px; wave w: rows 4w..4w+3 (2 n-tiles of
// 2 rows x 16 cols), all OC (MT m-tiles of 32). IC chunked by 32 into LDS.
// launch_bounds(256,4): VGPR cap 128 (kernel needs ~84; the (256,6) cap of
// ~80 caused catastrophic accumulator spill -> 3.5 GB scratch writes, R7).
// ---------------------------------------------------------------------------
template <int IC, int OC, int IN, int POOL>
__global__ __launch_bounds__(256, 4) void convmfma_kernel(
    const bf16* __restrict__ in, const bf16* __restrict__ wAp,
    const float* __restrict__ bias, bf16* __restrict__ out) {
    constexpr int MT = OC / 32;
    constexpr int CHUNKS = IC / 32;
    constexpr int ICD16 = IC / 16;
    __shared__ __align__(16) char smem[18 * 18 * 64];  // 20736 B

    const int tid = threadIdx.x;
    const int b = blockIdx.z;
    const int oh0 = blockIdx.y * 16;
    const int ow0 = blockIdx.x * 16;

    const int w   = tid >> 6;
    const int l   = tid & 63;
    const int lc4 = l & 15;
    const int r2  = (l >> 4) & 1;
    const int hh  = l >> 5;

    f32x16 acc[MT][2];
#pragma unroll
    for (int mt = 0; mt < MT; ++mt)
#pragma unroll
        for (int nt = 0; nt < 2; ++nt)
#pragma unroll
            for (int q = 0; q < 16; ++q) acc[mt][nt][q] = 0.f;

    for (int chunk = 0; chunk < CHUNKS; ++chunk) {
        if (chunk) __syncthreads();
        // ---- stage window rows oh0..+17, cols ow0..+17, ic chunk*32..+31 ----
        {
            const bf16* src = in + ((size_t)b * IN * IN) * IC + chunk * 32;
            for (int u = tid; u < 18 * 18 * 4; u += 256) {
                int slot = u & 3, cell = u >> 2;
                int row = cell / 18, col = cell - row * 18;
                int gr = oh0 + row, gc = ow0 + col;
                f32x4 v = {0.f, 0.f, 0.f, 0.f};
                if (gr < IN && gc < IN)
                    v = *(const f32x4*)(src + ((size_t)gr * IN + gc) * IC + slot * 8);
                *(f32x4*)(smem + cell * 64 + ((slot ^ ((col >> 1) & 3)) << 4)) = v;
            }
        }
        __syncthreads();

        // ---- K-loop: 9 taps x 2 ic-slices of 16 ----
#pragma unroll
        for (int kh = 0; kh < 3; ++kh) {
#pragma unroll
            for (int kw = 0; kw < 3; ++kw) {
                const int r = kh * 3 + kw;
                const int wincol = lc4 + kw;
                const int sx = (wincol >> 1) & 3;
#pragma unroll
                for (int cc = 0; cc < 2; ++cc) {
                    short8 af[MT];
#pragma unroll
                    for (int mt = 0; mt < MT; ++mt)
                        af[mt] = ((const short8*)wAp)[
                            (((mt * 9 + r) * ICD16) + chunk * 2 + cc) * 64 + l];
                    const int slot = cc * 2 + hh;
                    short8 bfr[2];
#pragma unroll
                    for (int nt = 0; nt < 2; ++nt) {
                        int cell = (4 * w + 2 * nt + r2 + kh) * 18 + wincol;
                        bfr[nt] = *(const short8*)(
                            smem + cell * 64 + ((slot ^ sx) << 4));
                    }
#pragma unroll
                    for (int mt = 0; mt < MT; ++mt)
#pragma unroll
                        for (int nt = 0; nt < 2; ++nt)
                            acc[mt][nt] = __builtin_amdgcn_mfma_f32_32x32x16_bf16(
                                af[mt], bfr[nt], acc[mt][nt], 0, 0, 0);
                }
            }
        }
    }

    // ---- epilogue: bias + leaky + 2x2 pool (rows at lane^16, cols lane^1) ----
    const bool wr = ((l & 17) == 0);
    const int pw = blockIdx.x * 8 + (lc4 >> 1);
#pragma unroll
    for (int mt = 0; mt < MT; ++mt) {
#pragma unroll
        for (int nt = 0; nt < 2; ++nt) {
            const int ph = blockIdx.y * 8 + 2 * w + nt;
#pragma unroll
            for (int g = 0; g < 4; ++g) {
                us4 o;
#pragma unroll
                for (int q2 = 0; q2 < 4; ++q2) {
                    int q = g * 4 + q2;
                    int oc = mt * 32 + 8 * g + 4 * hh + q2;
                    float v = acc[mt][nt][q] + bias[oc];
                    v = (v >= 0.f) ? v : 0.5f * v;
                    float m1 = fmaxf(v, __shfl_xor(v, 1));
                    float m  = fmaxf(m1, __shfl_xor(m1, 16));
                    o[q2] = f2bu(m);
                }
                if (wr && ph < POOL && pw < POOL)
                    *(us4*)(&out[((size_t)(b * POOL + ph) * POOL + pw) * OC +
                                 mt * 32 + 8 * g + 4 * hh]) = o;
            }
        }
    }
}

// ---------------------------------------------------------------------------
// conv4 (32->8, 3x2) + bias.  a3 NHWC bf16 -> out f32 [32][4800]
// ---------------------------------------------------------------------------
__global__ __launch_bounds__(256) void conv4_kernel(
    const bf16* __restrict__ a3, const float* __restrict__ wc4,
    const float* __restrict__ b4, float* __restrict__ out) {
    int i = blockIdx.x * 256 + threadIdx.x;
    if (i >= 32 * 4800) return;
    int b = i / 4800;
    int rem = i % 4800;
    int oc = rem / 600;
    int r2 = rem % 600;
    int oh = r2 / 25, ow = r2 % 25;

    float acc = b4[oc];
    int rr = 0;
#pragma unroll
    for (int kh = 0; kh < 3; ++kh) {
#pragma unroll
        for (int kw = 0; kw < 2; ++kw, ++rr) {
            const bf16* xp = a3 + ((size_t)(b * 26 + oh + kh) * 26 + (ow + kw)) * 32;
            const float* wp = wc4 + oc * 192 + rr * 32;
            short8 x0 = *(const short8*)(xp);
            short8 x1 = *(const short8*)(xp + 8);
            short8 x2 = *(const short8*)(xp + 16);
            short8 x3 = *(const short8*)(xp + 24);
#pragma unroll
            for (int j = 0; j < 8; ++j) {
                union { short s; unsigned short u; } u0{x0[j]}, u1{x1[j]}, u2{x2[j]}, u3{x3[j]};
                acc += wp[j]      * __bfloat162float(__hip_bfloat16_raw{u0.u});
                acc += wp[8 + j]  * __bfloat162float(__hip_bfloat16_raw{u1.u});
                acc += wp[16 + j] * __bfloat162float(__hip_bfloat16_raw{u2.u});
                acc += wp[24 + j] * __bfloat162float(__hip_bfloat16_raw{u3.u});
            }
        }
    }
    out[i] = acc;
}

// ---------------------------------------------------------------------------
extern "C" void kernel_launch(void* const* d_in, const int* in_sizes, int n_in,
                              void* d_out, int out_size, void* d_ws, size_t ws_size,
                              hipStream_t stream) {
    const float* x  = (const float*)d_in[0];
    const float* w1 = (const float*)d_in[1];
    const float* b1 = (const float*)d_in[2];
    const float* w2 = (const float*)d_in[3];
    const float* b2 = (const float*)d_in[4];
    const float* w3 = (const float*)d_in[5];
    const float* b3 = (const float*)d_in[6];
    const float* w4 = (const float*)d_in[7];
    const float* b4 = (const float*)d_in[8];
    float* out = (float*)d_out;

    char* ws = (char*)d_ws;
    size_t off = 0;
    auto alloc = [&](size_t bytes) {
        void* p = ws + off;
        off = (off + bytes + 255) & ~(size_t)255;
        return p;
    };
    bf16* a1 = (bf16*)alloc((size_t)32 * 111 * 111 * 128 * 2);  // NHWC
    bf16* a2 = (bf16*)alloc((size_t)32 * 54 * 54 * 64 * 2);     // NHWC
    bf16* a3 = (bf16*)alloc((size_t)32 * 26 * 26 * 32 * 2);     // NHWC
    float* w1t = (float*)alloc(1152 * 4);
    bf16* wAp2 = (bf16*)alloc(73728 * 2);
    bf16* wAp3 = (bf16*)alloc(18432 * 2);
    float* wc4 = (float*)alloc(1536 * 4);

    // binarize + pack all weights (one launch)
    binpack_kernel<<<dim3((94848 + 255) / 256), 256, 0, stream>>>(
        w1, w2, w3, w4, w1t, wAp2, wAp3, wc4);

    // conv1: x -> a1 [32,111,111,128]
    dim3 g1((111 * 28 + 1) / 2, 32);
    conv1_kernel<<<g1, 256, 0, stream>>>(x, w1t, b1, a1);

    // conv2: a1 -> a2 [32,54,54,64]  (conv extent 108x108)
    dim3 g2(7, 7, 32);
    convmfma_kernel<128, 64, 111, 54><<<g2, 256, 0, stream>>>(a1, wAp2, b2, a2);

    // conv3: a2 -> a3 [32,26,26,32]  (conv extent 52x52)
    dim3 g3(4, 4, 32);
    convmfma_kernel<64, 32, 54, 26><<<g3, 256, 0, stream>>>(a2, wAp3, b3, a3);

    // conv4: a3 -> out [32,4800]
    conv4_kernel<<<dim3((32 * 4800 + 255) / 256), 256, 0, stream>>>(
        a3, wc4, b4, out);
}

// Round 9
// 285.550 us; speedup vs baseline: 5.1203x; 1.1605x over previous
//
#include <hip/hip_runtime.h>
#include <hip/hip_bf16.h>

using bf16 = __hip_bfloat16;
typedef short  short8  __attribute__((ext_vector_type(8)));   // 8 bf16
typedef float  f32x4   __attribute__((ext_vector_type(4)));
typedef float  f32x16  __attribute__((ext_vector_type(16)));
typedef unsigned short us4 __attribute__((ext_vector_type(4)));

static __device__ __forceinline__ bf16  f2b(float v) { return __float2bfloat16(v); }
static __device__ __forceinline__ unsigned short f2bu(float v) {
    bf16 t = __float2bfloat16(v);
    return *(unsigned short*)&t;
}

// ---------------------------------------------------------------------------
// Pack binarized OIHW weights into 32x32x16 MFMA A-fragment order:
// frag f = (mt*9 + r)*(IC/16) + cc ; lane l holds oc = mt*32+(l&31),
// k-slice ic = cc*16 + (l>>5)*8 + j.
__device__ __forceinline__ void pack32_one(const float* __restrict__ w,
                                           bf16* __restrict__ o, int i, int IC) {
    int j = i & 7;
    int l = (i >> 3) & 63;
    int f = i >> 9;
    int ICD16 = IC >> 4;
    int cc = f % ICD16;
    int t  = f / ICD16;
    int r  = t % 9;
    int mt = t / 9;
    int oc = mt * 32 + (l & 31);
    int ic = cc * 16 + ((l >> 5) << 3) + j;
    o[i] = f2b((w[(oc * IC + ic) * 9 + r] >= 0.f) ? 1.f : -1.f);
}

// One merged binarize/pack kernel.
// w1m: conv1 weights in A-frag order: [mt][lane][8]; lane l holds
// ch = mt*32+(l&31), k = (l>>5)*8+j; tap k<9 else 0.
__global__ __launch_bounds__(256) void binpack_kernel(
    const float* __restrict__ w1, const float* __restrict__ w2,
    const float* __restrict__ w3, const float* __restrict__ w4,
    bf16* __restrict__ w1m, bf16* __restrict__ wA2,
    bf16* __restrict__ wA3, float* __restrict__ wc4) {
    int i = blockIdx.x * 256 + threadIdx.x;
    if (i < 73728) {
        pack32_one(w2, wA2, i, 128);
    } else if (i < 73728 + 18432) {
        pack32_one(w3, wA3, i - 73728, 64);
    } else if (i < 73728 + 18432 + 2048) {
        int k = i - (73728 + 18432);
        int j = k & 7, l = (k >> 3) & 63, mt = k >> 9;
        int ch = mt * 32 + (l & 31);
        int t = ((l >> 5) << 3) + j;
        w1m[k] = f2b(t < 9 ? ((w1[ch * 9 + t] >= 0.f) ? 1.f : -1.f) : 0.f);
    } else if (i < 73728 + 18432 + 2048 + 1536) {
        int k = i - (73728 + 18432 + 2048);    // w4 [8][32][6] -> wc4 [8][6][32]
        int oc = k / 192, rem = k % 192;
        int ic = rem / 6, r = rem % 6;
        wc4[oc * 192 + r * 32 + ic] = (w4[k] >= 0.f) ? 1.f : -1.f;
    }
}

// ---------------------------------------------------------------------------
// conv1 (1->128, 3x3) + bias + leaky + pool via MFMA 32x32x16.
// GEMM: M=128 ch (4 m-tiles), K=16 (9 taps + 7 zero-pad), N=32 lanes =
// 2 conv rows x 16 conv cols. Wave w -> pooled row ph0+w, cols pw0..pw0+7.
// Pool: shfl_xor(1) (col pair, lane bit0) + shfl_xor(16) (row pair, bit4).
// x f32 NCHW -> a1 bf16 NHWC.
// ---------------------------------------------------------------------------
__global__ __launch_bounds__(256, 4) void conv1_kernel(
    const float* __restrict__ x, const bf16* __restrict__ w1m,
    const float* __restrict__ b1, bf16* __restrict__ a1) {
    __shared__ float xt[10][20];
    const int tid = threadIdx.x;
    const int b = blockIdx.z;
    const int pw0 = blockIdx.x * 8;
    const int ph0 = blockIdx.y * 4;
    const int r0 = ph0 * 2;            // conv row base
    const int c0 = pw0 * 2;            // conv col base

    // stage x window [10][18] (clamped at image edge)
    if (tid < 180) {
        int row = tid / 18, col = tid - row * 18;
        int gr = r0 + row, gc = c0 + col;
        xt[row][col] = (gr < 224 && gc < 224)
                           ? x[((size_t)b * 224 + gr) * 224 + gc] : 0.f;
    }
    __syncthreads();

    const int w  = tid >> 6;
    const int l  = tid & 63;
    const int lc = l & 15;
    const int r2 = (l >> 4) & 1;
    const int hh = l >> 5;

    // A fragments (binarized weights), 4 m-tiles of 32 channels
    short8 af[4];
#pragma unroll
    for (int mt = 0; mt < 4; ++mt)
        af[mt] = ((const short8*)w1m)[mt * 64 + l];

    // B fragment: lane holds taps (hh*8+j) of conv px (row r0+2w+r2, col c0+lc)
    const int hl = 2 * w + r2;
    short8 bf;
    if (hh == 0) {
        bf[0] = (short)f2bu(xt[hl + 0][lc + 0]);
        bf[1] = (short)f2bu(xt[hl + 0][lc + 1]);
        bf[2] = (short)f2bu(xt[hl + 0][lc + 2]);
        bf[3] = (short)f2bu(xt[hl + 1][lc + 0]);
        bf[4] = (short)f2bu(xt[hl + 1][lc + 1]);
        bf[5] = (short)f2bu(xt[hl + 1][lc + 2]);
        bf[6] = (short)f2bu(xt[hl + 2][lc + 0]);
        bf[7] = (short)f2bu(xt[hl + 2][lc + 1]);
    } else {
        bf[0] = (short)f2bu(xt[hl + 2][lc + 2]);   // tap 8
        bf[1] = 0; bf[2] = 0; bf[3] = 0;
        bf[4] = 0; bf[5] = 0; bf[6] = 0; bf[7] = 0;
    }

    f32x16 acc[4];
#pragma unroll
    for (int mt = 0; mt < 4; ++mt) {
#pragma unroll
        for (int q = 0; q < 16; ++q) acc[mt][q] = 0.f;
        acc[mt] = __builtin_amdgcn_mfma_f32_32x32x16_bf16(af[mt], bf, acc[mt],
                                                          0, 0, 0);
    }

    // epilogue: bias + leaky + 2x2 pool + NHWC store
    const bool wr = ((l & 17) == 0);
    const int pw = pw0 + (lc >> 1);
    const int ph = ph0 + w;
    if (ph < 111 && pw < 111) {
#pragma unroll
        for (int mt = 0; mt < 4; ++mt) {
#pragma unroll
            for (int g = 0; g < 4; ++g) {
                f32x4 bias = *(const f32x4*)(b1 + mt * 32 + 8 * g + 4 * hh);
                us4 o;
#pragma unroll
                for (int q2 = 0; q2 < 4; ++q2) {
                    float v = acc[mt][g * 4 + q2] + bias[q2];
                    v = (v >= 0.f) ? v : 0.5f * v;
                    float m1 = fmaxf(v, __shfl_xor(v, 1));
                    float m  = fmaxf(m1, __shfl_xor(m1, 16));
                    o[q2] = f2bu(m);
                }
                if (wr)
                    *(us4*)(&a1[((size_t)(b * 111 + ph) * 111 + pw) * 128 +
                                mt * 32 + 8 * g + 4 * hh]) = o;
            }
        }
    }
}

// ---------------------------------------------------------------------------
// MFMA 32x32x16 implicit-GEMM conv3x3 + bias + leaky + maxpool2.
// Block: 256 thr, tile 16x16 conv px; wave w: rows 4w..4w+3 (2 n-tiles of
// 2 rows x 16 cols), all OC (MT m-tiles of 32). IC chunked by 32 into LDS.
// launch_bounds(256,4): VGPR cap 128 (kernel needs ~84; the (256,6) cap of
// ~80 caused catastrophic accumulator spill -> 3.5 GB scratch writes, R7).
// ---------------------------------------------------------------------------
template <int IC, int OC, int IN, int POOL>
__global__ __launch_bounds__(256, 4) void convmfma_kernel(
    const bf16* __restrict__ in, const bf16* __restrict__ wAp,
    const float* __restrict__ bias, bf16* __restrict__ out) {
    constexpr int MT = OC / 32;
    constexpr int CHUNKS = IC / 32;
    constexpr int ICD16 = IC / 16;
    __shared__ __align__(16) char smem[18 * 18 * 64];  // 20736 B

    const int tid = threadIdx.x;
    const int b = blockIdx.z;
    const int oh0 = blockIdx.y * 16;
    const int ow0 = blockIdx.x * 16;

    const int w   = tid >> 6;
    const int l   = tid & 63;
    const int lc4 = l & 15;
    const int r2  = (l >> 4) & 1;
    const int hh  = l >> 5;

    f32x16 acc[MT][2];
#pragma unroll
    for (int mt = 0; mt < MT; ++mt)
#pragma unroll
        for (int nt = 0; nt < 2; ++nt)
#pragma unroll
            for (int q = 0; q < 16; ++q) acc[mt][nt][q] = 0.f;

    for (int chunk = 0; chunk < CHUNKS; ++chunk) {
        if (chunk) __syncthreads();
        // ---- stage window rows oh0..+17, cols ow0..+17, ic chunk*32..+31 ----
        {
            const bf16* src = in + ((size_t)b * IN * IN) * IC + chunk * 32;
            for (int u = tid; u < 18 * 18 * 4; u += 256) {
                int slot = u & 3, cell = u >> 2;
                int row = cell / 18, col = cell - row * 18;
                int gr = oh0 + row, gc = ow0 + col;
                f32x4 v = {0.f, 0.f, 0.f, 0.f};
                if (gr < IN && gc < IN)
                    v = *(const f32x4*)(src + ((size_t)gr * IN + gc) * IC + slot * 8);
                *(f32x4*)(smem + cell * 64 + ((slot ^ ((col >> 1) & 3)) << 4)) = v;
            }
        }
        __syncthreads();

        // ---- K-loop: 9 taps x 2 ic-slices of 16 ----
#pragma unroll
        for (int kh = 0; kh < 3; ++kh) {
#pragma unroll
            for (int kw = 0; kw < 3; ++kw) {
                const int r = kh * 3 + kw;
                const int wincol = lc4 + kw;
                const int sx = (wincol >> 1) & 3;
#pragma unroll
                for (int cc = 0; cc < 2; ++cc) {
                    short8 af[MT];
#pragma unroll
                    for (int mt = 0; mt < MT; ++mt)
                        af[mt] = ((const short8*)wAp)[
                            (((mt * 9 + r) * ICD16) + chunk * 2 + cc) * 64 + l];
                    const int slot = cc * 2 + hh;
                    short8 bfr[2];
#pragma unroll
                    for (int nt = 0; nt < 2; ++nt) {
                        int cell = (4 * w + 2 * nt + r2 + kh) * 18 + wincol;
                        bfr[nt] = *(const short8*)(
                            smem + cell * 64 + ((slot ^ sx) << 4));
                    }
#pragma unroll
                    for (int mt = 0; mt < MT; ++mt)
#pragma unroll
                        for (int nt = 0; nt < 2; ++nt)
                            acc[mt][nt] = __builtin_amdgcn_mfma_f32_32x32x16_bf16(
                                af[mt], bfr[nt], acc[mt][nt], 0, 0, 0);
                }
            }
        }
    }

    // ---- epilogue: bias + leaky + 2x2 pool (rows at lane^16, cols lane^1) ----
    const bool wr = ((l & 17) == 0);
    const int pw = blockIdx.x * 8 + (lc4 >> 1);
#pragma unroll
    for (int mt = 0; mt < MT; ++mt) {
#pragma unroll
        for (int nt = 0; nt < 2; ++nt) {
            const int ph = blockIdx.y * 8 + 2 * w + nt;
#pragma unroll
            for (int g = 0; g < 4; ++g) {
                us4 o;
#pragma unroll
                for (int q2 = 0; q2 < 4; ++q2) {
                    int q = g * 4 + q2;
                    int oc = mt * 32 + 8 * g + 4 * hh + q2;
                    float v = acc[mt][nt][q] + bias[oc];
                    v = (v >= 0.f) ? v : 0.5f * v;
                    float m1 = fmaxf(v, __shfl_xor(v, 1));
                    float m  = fmaxf(m1, __shfl_xor(m1, 16));
                    o[q2] = f2bu(m);
                }
                if (wr && ph < POOL && pw < POOL)
                    *(us4*)(&out[((size_t)(b * POOL + ph) * POOL + pw) * OC +
                                 mt * 32 + 8 * g + 4 * hh]) = o;
            }
        }
    }
}

// ---------------------------------------------------------------------------
// conv4 (32->8, 3x2) + bias.  a3 NHWC bf16 -> out f32 [32][4800]
// ---------------------------------------------------------------------------
__global__ __launch_bounds__(256) void conv4_kernel(
    const bf16* __restrict__ a3, const float* __restrict__ wc4,
    const float* __restrict__ b4, float* __restrict__ out) {
    int i = blockIdx.x * 256 + threadIdx.x;
    if (i >= 32 * 4800) return;
    int b = i / 4800;
    int rem = i % 4800;
    int oc = rem / 600;
    int r2 = rem % 600;
    int oh = r2 / 25, ow = r2 % 25;

    float acc = b4[oc];
    int rr = 0;
#pragma unroll
    for (int kh = 0; kh < 3; ++kh) {
#pragma unroll
        for (int kw = 0; kw < 2; ++kw, ++rr) {
            const bf16* xp = a3 + ((size_t)(b * 26 + oh + kh) * 26 + (ow + kw)) * 32;
            const float* wp = wc4 + oc * 192 + rr * 32;
            short8 x0 = *(const short8*)(xp);
            short8 x1 = *(const short8*)(xp + 8);
            short8 x2 = *(const short8*)(xp + 16);
            short8 x3 = *(const short8*)(xp + 24);
#pragma unroll
            for (int j = 0; j < 8; ++j) {
                union { short s; unsigned short u; } u0{x0[j]}, u1{x1[j]}, u2{x2[j]}, u3{x3[j]};
                acc += wp[j]      * __bfloat162float(__hip_bfloat16_raw{u0.u});
                acc += wp[8 + j]  * __bfloat162float(__hip_bfloat16_raw{u1.u});
                acc += wp[16 + j] * __bfloat162float(__hip_bfloat16_raw{u2.u});
                acc += wp[24 + j] * __bfloat162float(__hip_bfloat16_raw{u3.u});
            }
        }
    }
    out[i] = acc;
}

// ---------------------------------------------------------------------------
extern "C" void kernel_launch(void* const* d_in, const int* in_sizes, int n_in,
                              void* d_out, int out_size, void* d_ws, size_t ws_size,
                              hipStream_t stream) {
    const float* x  = (const float*)d_in[0];
    const float* w1 = (const float*)d_in[1];
    const float* b1 = (const float*)d_in[2];
    const float* w2 = (const float*)d_in[3];
    const float* b2 = (const float*)d_in[4];
    const float* w3 = (const float*)d_in[5];
    const float* b3 = (const float*)d_in[6];
    const float* w4 = (const float*)d_in[7];
    const float* b4 = (const float*)d_in[8];
    float* out = (float*)d_out;

    char* ws = (char*)d_ws;
    size_t off = 0;
    auto alloc = [&](size_t bytes) {
        void* p = ws + off;
        off = (off + bytes + 255) & ~(size_t)255;
        return p;
    };
    bf16* a1 = (bf16*)alloc((size_t)32 * 111 * 111 * 128 * 2);  // NHWC
    bf16* a2 = (bf16*)alloc((size_t)32 * 54 * 54 * 64 * 2);     // NHWC
    bf16* a3 = (bf16*)alloc((size_t)32 * 26 * 26 * 32 * 2);     // NHWC
    bf16* w1m = (bf16*)alloc(2048 * 2);
    bf16* wAp2 = (bf16*)alloc(73728 * 2);
    bf16* wAp3 = (bf16*)alloc(18432 * 2);
    float* wc4 = (float*)alloc(1536 * 4);

    // binarize + pack all weights (one launch)
    binpack_kernel<<<dim3((95744 + 255) / 256), 256, 0, stream>>>(
        w1, w2, w3, w4, w1m, wAp2, wAp3, wc4);

    // conv1: x -> a1 [32,111,111,128]  (MFMA, 8x4 pooled px per block)
    dim3 g1(14, 28, 32);
    conv1_kernel<<<g1, 256, 0, stream>>>(x, w1m, b1, a1);

    // conv2: a1 -> a2 [32,54,54,64]  (conv extent 108x108)
    dim3 g2(7, 7, 32);
    convmfma_kernel<128, 64, 111, 54><<<g2, 256, 0, stream>>>(a1, wAp2, b2, a2);

    // conv3: a2 -> a3 [32,26,26,32]  (conv extent 52x52)
    dim3 g3(4, 4, 32);
    convmfma_kernel<64, 32, 54, 26><<<g3, 256, 0, stream>>>(a2, wAp3, b3, a3);

    // conv4: a3 -> out [32,4800]
    conv4_kernel<<<dim3((32 * 4800 + 255) / 256), 256, 0, stream>>>(
        a3, wc4, b4, out);
}

// Round 13
// 258.036 us; speedup vs baseline: 5.6662x; 1.1066x over previous
//
#include <hip/hip_runtime.h>
#include <hip/hip_bf16.h>

using bf16 = __hip_bfloat16;
typedef short  short8  __attribute__((ext_vector_type(8)));   // 8 bf16
typedef float  f32x4   __attribute__((ext_vector_type(4)));
typedef float  f32x16  __attribute__((ext_vector_type(16)));
typedef unsigned short us4 __attribute__((ext_vector_type(4)));

static __device__ __forceinline__ bf16  f2b(float v) { return __float2bfloat16(v); }
static __device__ __forceinline__ unsigned short f2bu(float v) {
    bf16 t = __float2bfloat16(v);
    return *(unsigned short*)&t;
}

// ---------------------------------------------------------------------------
// Pack binarized OIHW weights into 32x32x16 MFMA A-fragment order:
// frag f = (mt*9 + r)*(IC/16) + cc ; lane l holds oc = mt*32+(l&31),
// k-slice ic = cc*16 + (l>>5)*8 + j.
__device__ __forceinline__ void pack32_one(const float* __restrict__ w,
                                           bf16* __restrict__ o, int i, int IC) {
    int j = i & 7;
    int l = (i >> 3) & 63;
    int f = i >> 9;
    int ICD16 = IC >> 4;
    int cc = f % ICD16;
    int t  = f / ICD16;
    int r  = t % 9;
    int mt = t / 9;
    int oc = mt * 32 + (l & 31);
    int ic = cc * 16 + ((l >> 5) << 3) + j;
    o[i] = f2b((w[(oc * IC + ic) * 9 + r] >= 0.f) ? 1.f : -1.f);
}

// One merged binarize/pack kernel.
// w1m: conv1 weights in A-frag order: [mt][lane][8]; lane l holds
// ch = mt*32+(l&31), k = (l>>5)*8+j; tap k<9 else 0.
__global__ __launch_bounds__(256) void binpack_kernel(
    const float* __restrict__ w1, const float* __restrict__ w2,
    const float* __restrict__ w3, const float* __restrict__ w4,
    bf16* __restrict__ w1m, bf16* __restrict__ wA2,
    bf16* __restrict__ wA3, float* __restrict__ wc4) {
    int i = blockIdx.x * 256 + threadIdx.x;
    if (i < 73728) {
        pack32_one(w2, wA2, i, 128);
    } else if (i < 73728 + 18432) {
        pack32_one(w3, wA3, i - 73728, 64);
    } else if (i < 73728 + 18432 + 2048) {
        int k = i - (73728 + 18432);
        int j = k & 7, l = (k >> 3) & 63, mt = k >> 9;
        int ch = mt * 32 + (l & 31);
        int t = ((l >> 5) << 3) + j;
        w1m[k] = f2b(t < 9 ? ((w1[ch * 9 + t] >= 0.f) ? 1.f : -1.f) : 0.f);
    } else if (i < 73728 + 18432 + 2048 + 1536) {
        int k = i - (73728 + 18432 + 2048);    // w4 [8][32][6] -> wc4 [8][6][32]
        int oc = k / 192, rem = k % 192;
        int ic = rem / 6, r = rem % 6;
        wc4[oc * 192 + r * 32 + ic] = (w4[k] >= 0.f) ? 1.f : -1.f;
    }
}

// ---------------------------------------------------------------------------
// conv1 (1->128, 3x3) + bias + leaky + pool via MFMA 32x32x16.
// GEMM: M=128 ch (4 m-tiles), K=16 (9 taps + 7 zero-pad), N=32 lanes =
// 2 conv rows x 16 conv cols. Wave w -> pooled row ph0+w, cols pw0..pw0+7.
// ---------------------------------------------------------------------------
__global__ __launch_bounds__(256, 4) void conv1_kernel(
    const float* __restrict__ x, const bf16* __restrict__ w1m,
    const float* __restrict__ b1, bf16* __restrict__ a1) {
    __shared__ float xt[10][20];
    const int tid = threadIdx.x;
    const int b = blockIdx.z;
    const int pw0 = blockIdx.x * 8;
    const int ph0 = blockIdx.y * 4;
    const int r0 = ph0 * 2;            // conv row base
    const int c0 = pw0 * 2;            // conv col base

    // stage x window [10][18] (clamped at image edge)
    if (tid < 180) {
        int row = tid / 18, col = tid - row * 18;
        int gr = r0 + row, gc = c0 + col;
        xt[row][col] = (gr < 224 && gc < 224)
                           ? x[((size_t)b * 224 + gr) * 224 + gc] : 0.f;
    }
    __syncthreads();

    const int w  = tid >> 6;
    const int l  = tid & 63;
    const int lc = l & 15;
    const int r2 = (l >> 4) & 1;
    const int hh = l >> 5;

    // A fragments (binarized weights), 4 m-tiles of 32 channels
    short8 af[4];
#pragma unroll
    for (int mt = 0; mt < 4; ++mt)
        af[mt] = ((const short8*)w1m)[mt * 64 + l];

    // B fragment: lane holds taps (hh*8+j) of conv px (row r0+2w+r2, col c0+lc)
    const int hl = 2 * w + r2;
    short8 bf;
    if (hh == 0) {
        bf[0] = (short)f2bu(xt[hl + 0][lc + 0]);
        bf[1] = (short)f2bu(xt[hl + 0][lc + 1]);
        bf[2] = (short)f2bu(xt[hl + 0][lc + 2]);
        bf[3] = (short)f2bu(xt[hl + 1][lc + 0]);
        bf[4] = (short)f2bu(xt[hl + 1][lc + 1]);
        bf[5] = (short)f2bu(xt[hl + 1][lc + 2]);
        bf[6] = (short)f2bu(xt[hl + 2][lc + 0]);
        bf[7] = (short)f2bu(xt[hl + 2][lc + 1]);
    } else {
        bf[0] = (short)f2bu(xt[hl + 2][lc + 2]);   // tap 8
        bf[1] = 0; bf[2] = 0; bf[3] = 0;
        bf[4] = 0; bf[5] = 0; bf[6] = 0; bf[7] = 0;
    }

    f32x16 acc[4];
#pragma unroll
    for (int mt = 0; mt < 4; ++mt) {
#pragma unroll
        for (int q = 0; q < 16; ++q) acc[mt][q] = 0.f;
        acc[mt] = __builtin_amdgcn_mfma_f32_32x32x16_bf16(af[mt], bf, acc[mt],
                                                          0, 0, 0);
    }

    // epilogue: bias + leaky + 2x2 pool + NHWC store
    const bool wr = ((l & 17) == 0);
    const int pw = pw0 + (lc >> 1);
    const int ph = ph0 + w;
    if (ph < 111 && pw < 111) {
#pragma unroll
        for (int mt = 0; mt < 4; ++mt) {
#pragma unroll
            for (int g = 0; g < 4; ++g) {
                f32x4 bias = *(const f32x4*)(b1 + mt * 32 + 8 * g + 4 * hh);
                us4 o;
#pragma unroll
                for (int q2 = 0; q2 < 4; ++q2) {
                    float v = acc[mt][g * 4 + q2] + bias[q2];
                    v = (v >= 0.f) ? v : 0.5f * v;
                    float m1 = fmaxf(v, __shfl_xor(v, 1));
                    float m  = fmaxf(m1, __shfl_xor(m1, 16));
                    o[q2] = f2bu(m);
                }
                if (wr)
                    *(us4*)(&a1[((size_t)(b * 111 + ph) * 111 + pw) * 128 +
                                mt * 32 + 8 * g + 4 * hh]) = o;
            }
        }
    }
}

// ---------------------------------------------------------------------------
// MFMA 32x32x16 implicit-GEMM conv3x3 + bias + leaky + maxpool2.
// R10 remap for fragment reuse (R9 was latency-bound: MfmaUtil 20%,
// VALUBusy 18%, only 2 MFMAs per ds_read): N = 1 row x 32 cols; wave w
// owns conv rows 2w,2w+1 (nt=2). Row-overlap nt+kh lets 4 brow[] ds_reads
// feed 12 MFMAs per (cc,kw) group (3 MFMA/read; A-frags reused 2x).
// Window [10][34][4x16B] = 21.8 KB, swizzle slot^((col>>1)&3).
// launch_bounds(256,2): VGPR cap 256 — do NOT tighten (R7: a too-tight cap
// spilled accumulators -> 3.5 GB scratch traffic).
// Pool: row pair in-lane (nt), col pair shfl_xor(1); bias+leaky after max
// (monotonic => identical result).
// ---------------------------------------------------------------------------
template <int IC, int OC, int IN, int POOL>
__global__ __launch_bounds__(256, 2) void convmfma_kernel(
    const bf16* __restrict__ in, const bf16* __restrict__ wAp,
    const float* __restrict__ bias, bf16* __restrict__ out) {
    constexpr int MT = OC / 32;
    constexpr int CHUNKS = IC / 32;
    constexpr int ICD16 = IC / 16;
    constexpr int WROW = 10, WCOL = 34;
    __shared__ __align__(16) char smem[WROW * WCOL * 64];  // 21760 B

    const int tid = threadIdx.x;
    const int b = blockIdx.z;
    const int oh0 = blockIdx.y * 8;     // conv row base (8 rows/block)
    const int ow0 = blockIdx.x * 32;    // conv col base (32 cols/block)

    const int w  = tid >> 6;            // wave -> conv rows 2w, 2w+1
    const int l  = tid & 63;
    const int n  = l & 31;              // conv col within tile
    const int hh = l >> 5;              // k-half

    f32x16 acc[MT][2];
#pragma unroll
    for (int mt = 0; mt < MT; ++mt)
#pragma unroll
        for (int nt = 0; nt < 2; ++nt)
#pragma unroll
            for (int q = 0; q < 16; ++q) acc[mt][nt][q] = 0.f;

    for (int chunk = 0; chunk < CHUNKS; ++chunk) {
        if (chunk) __syncthreads();
        // ---- stage window [10][34] cells x 4 slots of 16B, swizzled ----
        {
            const bf16* src = in + (size_t)b * IN * IN * IC + chunk * 32;
            for (int u = tid; u < WROW * WCOL * 4; u += 256) {
                int slot = u & 3, cell = u >> 2;
                int row = cell / WCOL, col = cell - row * WCOL;
                int gr = oh0 + row, gc = ow0 + col;
                f32x4 v = {0.f, 0.f, 0.f, 0.f};
                if (gr < IN && gc < IN)
                    v = *(const f32x4*)(src + ((size_t)gr * IN + gc) * IC + slot * 8);
                *(f32x4*)(smem + cell * 64 + ((slot ^ ((col >> 1) & 3)) << 4)) = v;
            }
        }
        __syncthreads();

#pragma unroll
        for (int cc = 0; cc < 2; ++cc) {
#pragma unroll
            for (int kw = 0; kw < 3; ++kw) {
                const int wincol = n + kw;
                const int sx = (wincol >> 1) & 3;
                const int slot = cc * 2 + hh;
                // 4 window-row fragments serve all (kh, nt) combos
                short8 brow[4];
#pragma unroll
                for (int ar = 0; ar < 4; ++ar) {
                    int cell = (2 * w + ar) * WCOL + wincol;
                    brow[ar] = *(const short8*)(
                        smem + cell * 64 + ((slot ^ sx) << 4));
                }
#pragma unroll
                for (int kh = 0; kh < 3; ++kh) {
                    const int r = kh * 3 + kw;
                    short8 af[MT];
#pragma unroll
                    for (int mt = 0; mt < MT; ++mt)
                        af[mt] = ((const short8*)wAp)[
                            (((mt * 9 + r) * ICD16) + chunk * 2 + cc) * 64 + l];
#pragma unroll
                    for (int nt = 0; nt < 2; ++nt)
#pragma unroll
                        for (int mt = 0; mt < MT; ++mt)
                            acc[mt][nt] = __builtin_amdgcn_mfma_f32_32x32x16_bf16(
                                af[mt], brow[nt + kh], acc[mt][nt], 0, 0, 0);
                }
            }
        }
    }

    // ---- epilogue: 2x2 pool (rows in-lane, cols shfl_xor(1)) + bias + leaky ----
    const int pw = blockIdx.x * 16 + (n >> 1);
    const int ph = blockIdx.y * 4 + w;
    const bool wr = ((l & 1) == 0) && ph < POOL && pw < POOL;
#pragma unroll
    for (int mt = 0; mt < MT; ++mt) {
#pragma unroll
        for (int g = 0; g < 4; ++g) {
            f32x4 bs = *(const f32x4*)(bias + mt * 32 + 8 * g + 4 * hh);
            us4 o;
#pragma unroll
            for (int q2 = 0; q2 < 4; ++q2) {
                int q = g * 4 + q2;
                float v = fmaxf(acc[mt][0][q], acc[mt][1][q]);  // row pair
                v = fmaxf(v, __shfl_xor(v, 1));                  // col pair
                v += bs[q2];
                v = (v >= 0.f) ? v : 0.5f * v;
                o[q2] = f2bu(v);
            }
            if (wr)
                *(us4*)(&out[((size_t)(b * POOL + ph) * POOL + pw) * OC +
                             mt * 32 + 8 * g + 4 * hh]) = o;
        }
    }
}

// ---------------------------------------------------------------------------
// conv4 (32->8, 3x2) + bias.  a3 NHWC bf16 -> out f32 [32][4800]
// ---------------------------------------------------------------------------
__global__ __launch_bounds__(256) void conv4_kernel(
    const bf16* __restrict__ a3, const float* __restrict__ wc4,
    const float* __restrict__ b4, float* __restrict__ out) {
    int i = blockIdx.x * 256 + threadIdx.x;
    if (i >= 32 * 4800) return;
    int b = i / 4800;
    int rem = i % 4800;
    int oc = rem / 600;
    int r2 = rem % 600;
    int oh = r2 / 25, ow = r2 % 25;

    float acc = b4[oc];
    int rr = 0;
#pragma unroll
    for (int kh = 0; kh < 3; ++kh) {
#pragma unroll
        for (int kw = 0; kw < 2; ++kw, ++rr) {
            const bf16* xp = a3 + ((size_t)(b * 26 + oh + kh) * 26 + (ow + kw)) * 32;
            const float* wp = wc4 + oc * 192 + rr * 32;
            short8 x0 = *(const short8*)(xp);
            short8 x1 = *(const short8*)(xp + 8);
            short8 x2 = *(const short8*)(xp + 16);
            short8 x3 = *(const short8*)(xp + 24);
#pragma unroll
            for (int j = 0; j < 8; ++j) {
                union { short s; unsigned short u; } u0{x0[j]}, u1{x1[j]}, u2{x2[j]}, u3{x3[j]};
                acc += wp[j]      * __bfloat162float(__hip_bfloat16_raw{u0.u});
                acc += wp[8 + j]  * __bfloat162float(__hip_bfloat16_raw{u1.u});
                acc += wp[16 + j] * __bfloat162float(__hip_bfloat16_raw{u2.u});
                acc += wp[24 + j] * __bfloat162float(__hip_bfloat16_raw{u3.u});
            }
        }
    }
    out[i] = acc;
}

// ---------------------------------------------------------------------------
extern "C" void kernel_launch(void* const* d_in, const int* in_sizes, int n_in,
                              void* d_out, int out_size, void* d_ws, size_t ws_size,
                              hipStream_t stream) {
    const float* x  = (const float*)d_in[0];
    const float* w1 = (const float*)d_in[1];
    const float* b1 = (const float*)d_in[2];
    const float* w2 = (const float*)d_in[3];
    const float* b2 = (const float*)d_in[4];
    const float* w3 = (const float*)d_in[5];
    const float* b3 = (const float*)d_in[6];
    const float* w4 = (const float*)d_in[7];
    const float* b4 = (const float*)d_in[8];
    float* out = (float*)d_out;

    char* ws = (char*)d_ws;
    size_t off = 0;
    auto alloc = [&](size_t bytes) {
        void* p = ws + off;
        off = (off + bytes + 255) & ~(size_t)255;
        return p;
    };
    bf16* a1 = (bf16*)alloc((size_t)32 * 111 * 111 * 128 * 2);  // NHWC
    bf16* a2 = (bf16*)alloc((size_t)32 * 54 * 54 * 64 * 2);     // NHWC
    bf16* a3 = (bf16*)alloc((size_t)32 * 26 * 26 * 32 * 2);     // NHWC
    bf16* w1m = (bf16*)alloc(2048 * 2);
    bf16* wAp2 = (bf16*)alloc(73728 * 2);
    bf16* wAp3 = (bf16*)alloc(18432 * 2);
    float* wc4 = (float*)alloc(1536 * 4);

    // binarize + pack all weights (one launch)
    binpack_kernel<<<dim3((95744 + 255) / 256), 256, 0, stream>>>(
        w1, w2, w3, w4, w1m, wAp2, wAp3, wc4);

    // conv1: x -> a1 [32,111,111,128]  (MFMA, 8x4 pooled px per block)
    dim3 g1(14, 28, 32);
    conv1_kernel<<<g1, 256, 0, stream>>>(x, w1m, b1, a1);

    // conv2: a1 -> a2 [32,54,54,64]  (conv extent 108x108)
    dim3 g2(4, 14, 32);
    convmfma_kernel<128, 64, 111, 54><<<g2, 256, 0, stream>>>(a1, wAp2, b2, a2);

    // conv3: a2 -> a3 [32,26,26,32]  (conv extent 52x52)
    dim3 g3(2, 7, 32);
    convmfma_kernel<64, 32, 54, 26><<<g3, 256, 0, stream>>>(a2, wAp3, b3, a3);

    // conv4: a3 -> out [32,4800]
    conv4_kernel<<<dim3((32 * 4800 + 255) / 256), 256, 0, stream>>>(
        a3, wc4, b4, out);
}

// Round 15
// 238.056 us; speedup vs baseline: 6.1418x; 1.0839x over previous
//
#include <hip/hip_runtime.h>
#include <hip/hip_bf16.h>

using bf16 = __hip_bfloat16;
typedef short  short8  __attribute__((ext_vector_type(8)));   // 8 bf16
typedef float  f32x4   __attribute__((ext_vector_type(4)));
typedef float  f32x16  __attribute__((ext_vector_type(16)));
typedef unsigned short us4 __attribute__((ext_vector_type(4)));

static __device__ __forceinline__ bf16  f2b(float v) { return __float2bfloat16(v); }
static __device__ __forceinline__ unsigned short f2bu(float v) {
    bf16 t = __float2bfloat16(v);
    return *(unsigned short*)&t;
}

// ---------------------------------------------------------------------------
// Pack binarized OIHW weights into 32x32x16 MFMA A-fragment order:
// frag f = (mt*9 + r)*(IC/16) + cc ; lane l holds oc = mt*32+(l&31),
// k-slice ic = cc*16 + (l>>5)*8 + j.
__device__ __forceinline__ void pack32_one(const float* __restrict__ w,
                                           bf16* __restrict__ o, int i, int IC) {
    int j = i & 7;
    int l = (i >> 3) & 63;
    int f = i >> 9;
    int ICD16 = IC >> 4;
    int cc = f % ICD16;
    int t  = f / ICD16;
    int r  = t % 9;
    int mt = t / 9;
    int oc = mt * 32 + (l & 31);
    int ic = cc * 16 + ((l >> 5) << 3) + j;
    o[i] = f2b((w[(oc * IC + ic) * 9 + r] >= 0.f) ? 1.f : -1.f);
}

// One merged binarize/pack kernel.
__global__ __launch_bounds__(256) void binpack_kernel(
    const float* __restrict__ w1, const float* __restrict__ w2,
    const float* __restrict__ w3, const float* __restrict__ w4,
    bf16* __restrict__ w1m, bf16* __restrict__ wA2,
    bf16* __restrict__ wA3, float* __restrict__ wc4) {
    int i = blockIdx.x * 256 + threadIdx.x;
    if (i < 73728) {
        pack32_one(w2, wA2, i, 128);
    } else if (i < 73728 + 18432) {
        pack32_one(w3, wA3, i - 73728, 64);
    } else if (i < 73728 + 18432 + 2048) {
        int k = i - (73728 + 18432);
        int j = k & 7, l = (k >> 3) & 63, mt = k >> 9;
        int ch = mt * 32 + (l & 31);
        int t = ((l >> 5) << 3) + j;
        w1m[k] = f2b(t < 9 ? ((w1[ch * 9 + t] >= 0.f) ? 1.f : -1.f) : 0.f);
    } else if (i < 73728 + 18432 + 2048 + 1536) {
        int k = i - (73728 + 18432 + 2048);    // w4 [8][32][6] -> wc4 [8][6][32]
        int oc = k / 192, rem = k % 192;
        int ic = rem / 6, r = rem % 6;
        wc4[oc * 192 + r * 32 + ic] = (w4[k] >= 0.f) ? 1.f : -1.f;
    }
}

// ---------------------------------------------------------------------------
// conv1 (1->128, 3x3) + bias + leaky + pool via MFMA 32x32x16.
// R14: N = 1 conv row x 32 cols; wave w -> pooled row ph0+w via 2 nt accs
// (conv rows 2(ph0+w), +1). Row-pool in-lane, col-pool shfl_xor(1):
// swizzles/output cut 4x vs R13 (which pooled via lane^1 AND lane^16).
// ---------------------------------------------------------------------------
__global__ __launch_bounds__(256, 2) void conv1_kernel(
    const float* __restrict__ x, const bf16* __restrict__ w1m,
    const float* __restrict__ b1, bf16* __restrict__ a1) {
    __shared__ float xt[10][34];
    const int tid = threadIdx.x;
    const int b = blockIdx.z;
    const int pw0 = blockIdx.x * 16;   // pooled col base
    const int ph0 = blockIdx.y * 4;    // pooled row base
    const int r0 = ph0 * 2;            // conv row base
    const int c0 = pw0 * 2;            // conv col base

    // stage x window [10][34] (clamped at image edge)
    for (int u = tid; u < 10 * 34; u += 256) {
        int row = u / 34, col = u - row * 34;
        int gr = r0 + row, gc = c0 + col;
        xt[row][col] = (gr < 224 && gc < 224)
                           ? x[((size_t)b * 224 + gr) * 224 + gc] : 0.f;
    }
    __syncthreads();

    const int w  = tid >> 6;
    const int l  = tid & 63;
    const int n  = l & 31;
    const int hh = l >> 5;

    // A fragments (binarized weights), 4 m-tiles of 32 channels
    short8 af[4];
#pragma unroll
    for (int mt = 0; mt < 4; ++mt)
        af[mt] = ((const short8*)w1m)[mt * 64 + l];

    // B fragments: nt in {0,1} -> conv row 2w+nt within window; col n.
    short8 bfr[2];
#pragma unroll
    for (int nt = 0; nt < 2; ++nt) {
        const int hl = 2 * w + nt;
        short8 bf;
        if (hh == 0) {
            bf[0] = (short)f2bu(xt[hl + 0][n + 0]);
            bf[1] = (short)f2bu(xt[hl + 0][n + 1]);
            bf[2] = (short)f2bu(xt[hl + 0][n + 2]);
            bf[3] = (short)f2bu(xt[hl + 1][n + 0]);
            bf[4] = (short)f2bu(xt[hl + 1][n + 1]);
            bf[5] = (short)f2bu(xt[hl + 1][n + 2]);
            bf[6] = (short)f2bu(xt[hl + 2][n + 0]);
            bf[7] = (short)f2bu(xt[hl + 2][n + 1]);
        } else {
            bf[0] = (short)f2bu(xt[hl + 2][n + 2]);   // tap 8
            bf[1] = 0; bf[2] = 0; bf[3] = 0;
            bf[4] = 0; bf[5] = 0; bf[6] = 0; bf[7] = 0;
        }
        bfr[nt] = bf;
    }

    f32x16 acc[4][2];
#pragma unroll
    for (int mt = 0; mt < 4; ++mt)
#pragma unroll
        for (int nt = 0; nt < 2; ++nt) {
#pragma unroll
            for (int q = 0; q < 16; ++q) acc[mt][nt][q] = 0.f;
            acc[mt][nt] = __builtin_amdgcn_mfma_f32_32x32x16_bf16(
                af[mt], bfr[nt], acc[mt][nt], 0, 0, 0);
        }

    // epilogue: 2x2 pool (rows in-lane, cols shfl_xor(1)) + bias + leaky
    const int pw = pw0 + (n >> 1);
    const int ph = ph0 + w;
    const bool wr = ((l & 1) == 0) && ph < 111 && pw < 111;
#pragma unroll
    for (int mt = 0; mt < 4; ++mt) {
#pragma unroll
        for (int g = 0; g < 4; ++g) {
            f32x4 bs = *(const f32x4*)(b1 + mt * 32 + 8 * g + 4 * hh);
            us4 o;
#pragma unroll
            for (int q2 = 0; q2 < 4; ++q2) {
                int q = g * 4 + q2;
                float v = fmaxf(acc[mt][0][q], acc[mt][1][q]);  // row pair
                v = fmaxf(v, __shfl_xor(v, 1));                  // col pair
                v += bs[q2];
                v = fmaxf(v, 0.5f * v);                          // leaky(0.5)
                o[q2] = f2bu(v);
            }
            if (wr)
                *(us4*)(&a1[((size_t)(b * 111 + ph) * 111 + pw) * 128 +
                            mt * 32 + 8 * g + 4 * hh]) = o;
        }
    }
}

// ---------------------------------------------------------------------------
// MFMA 32x32x16 implicit-GEMM conv3x3 + bias + leaky + maxpool2.
// R14: wave owns 4 conv rows (acc[MT][4]); 6 brow ds_reads per (cc,kw)
// feed 24 MFMAs (4 MFMA/read, A reused 4x). A-frags batch-loaded per
// (cc,kw) ahead of the MFMA cluster (R13: loads inside kh loop, VGPR=64,
// MfmaUtil 29% = dependency-stalled). Window [18][34], 39.2 KB LDS.
// Swizzle ((col>>1)^(col>>3))&3 breaks the n+8/16/24 bank aliasing of the
// old (col>>1)&3 (R13: 2.75M conflict cycles).
// launch_bounds(256,2): VGPR cap 256 — do NOT tighten (R7: tight cap
// spilled accumulators -> 3.5 GB scratch traffic).
// ---------------------------------------------------------------------------
template <int IC, int OC, int IN, int POOL>
__global__ __launch_bounds__(256, 2) void convmfma_kernel(
    const bf16* __restrict__ in, const bf16* __restrict__ wAp,
    const float* __restrict__ bias, bf16* __restrict__ out) {
    constexpr int MT = OC / 32;
    constexpr int CHUNKS = IC / 32;
    constexpr int ICD16 = IC / 16;
    constexpr int WROW = 18, WCOL = 34;
    __shared__ __align__(16) char smem[WROW * WCOL * 64];  // 39168 B

    const int tid = threadIdx.x;
    const int b = blockIdx.z;
    const int oh0 = blockIdx.y * 16;    // conv row base (16 rows/block)
    const int ow0 = blockIdx.x * 32;    // conv col base (32 cols/block)

    const int w  = tid >> 6;            // wave -> conv rows 4w..4w+3
    const int l  = tid & 63;
    const int n  = l & 31;              // conv col within tile
    const int hh = l >> 5;              // k-half

    f32x16 acc[MT][4];
#pragma unroll
    for (int mt = 0; mt < MT; ++mt)
#pragma unroll
        for (int nt = 0; nt < 4; ++nt)
#pragma unroll
            for (int q = 0; q < 16; ++q) acc[mt][nt][q] = 0.f;

    for (int chunk = 0; chunk < CHUNKS; ++chunk) {
        if (chunk) __syncthreads();
        // ---- stage window [18][34] cells x 4 slots of 16B, swizzled ----
        {
            const bf16* src = in + (size_t)b * IN * IN * IC + chunk * 32;
            for (int u = tid; u < WROW * WCOL * 4; u += 256) {
                int slot = u & 3, cell = u >> 2;
                int row = cell / WCOL, col = cell - row * WCOL;
                int gr = oh0 + row, gc = ow0 + col;
                f32x4 v = {0.f, 0.f, 0.f, 0.f};
                if (gr < IN && gc < IN)
                    v = *(const f32x4*)(src + ((size_t)gr * IN + gc) * IC + slot * 8);
                int sx = ((col >> 1) ^ (col >> 3)) & 3;
                *(f32x4*)(smem + cell * 64 + ((slot ^ sx) << 4)) = v;
            }
        }
        __syncthreads();

#pragma unroll
        for (int cc = 0; cc < 2; ++cc) {
#pragma unroll
            for (int kw = 0; kw < 3; ++kw) {
                // ---- A fragments batched: mt x kh (6 indep L2 loads) ----
                short8 af[MT][3];
#pragma unroll
                for (int mt = 0; mt < MT; ++mt)
#pragma unroll
                    for (int kh = 0; kh < 3; ++kh)
                        af[mt][kh] = ((const short8*)wAp)[
                            (((mt * 9 + kh * 3 + kw) * ICD16) +
                             chunk * 2 + cc) * 64 + l];
                // ---- B rows batched: 6 ds_read_b128 ----
                const int col = n + kw;
                const int sx = ((col >> 1) ^ (col >> 3)) & 3;
                const int slot = cc * 2 + hh;
                short8 brow[6];
#pragma unroll
                for (int ar = 0; ar < 6; ++ar) {
                    int cell = (4 * w + ar) * WCOL + col;
                    brow[ar] = *(const short8*)(
                        smem + cell * 64 + ((slot ^ sx) << 4));
                }
                // ---- 24 MFMAs (MT=2) ----
#pragma unroll
                for (int kh = 0; kh < 3; ++kh)
#pragma unroll
                    for (int nt = 0; nt < 4; ++nt)
#pragma unroll
                        for (int mt = 0; mt < MT; ++mt)
                            acc[mt][nt] = __builtin_amdgcn_mfma_f32_32x32x16_bf16(
                                af[mt][kh], brow[nt + kh], acc[mt][nt], 0, 0, 0);
            }
        }
    }

    // ---- epilogue: 2x2 pool (rows in-lane, cols shfl_xor(1)) + bias + leaky ----
    const int pw = blockIdx.x * 16 + (n >> 1);
#pragma unroll
    for (int ntp = 0; ntp < 2; ++ntp) {
        const int ph = blockIdx.y * 8 + 2 * w + ntp;
        const bool wr = ((l & 1) == 0) && ph < POOL && pw < POOL;
#pragma unroll
        for (int mt = 0; mt < MT; ++mt) {
#pragma unroll
            for (int g = 0; g < 4; ++g) {
                f32x4 bs = *(const f32x4*)(bias + mt * 32 + 8 * g + 4 * hh);
                us4 o;
#pragma unroll
                for (int q2 = 0; q2 < 4; ++q2) {
                    int q = g * 4 + q2;
                    float v = fmaxf(acc[mt][2 * ntp][q], acc[mt][2 * ntp + 1][q]);
                    v = fmaxf(v, __shfl_xor(v, 1));
                    v += bs[q2];
                    v = fmaxf(v, 0.5f * v);                      // leaky(0.5)
                    o[q2] = f2bu(v);
                }
                if (wr)
                    *(us4*)(&out[((size_t)(b * POOL + ph) * POOL + pw) * OC +
                                 mt * 32 + 8 * g + 4 * hh]) = o;
            }
        }
    }
}

// ---------------------------------------------------------------------------
// conv4 (32->8, 3x2) + bias.  a3 NHWC bf16 -> out f32 [32][4800]
// ---------------------------------------------------------------------------
__global__ __launch_bounds__(256) void conv4_kernel(
    const bf16* __restrict__ a3, const float* __restrict__ wc4,
    const float* __restrict__ b4, float* __restrict__ out) {
    int i = blockIdx.x * 256 + threadIdx.x;
    if (i >= 32 * 4800) return;
    int b = i / 4800;
    int rem = i % 4800;
    int oc = rem / 600;
    int r2 = rem % 600;
    int oh = r2 / 25, ow = r2 % 25;

    float acc = b4[oc];
    int rr = 0;
#pragma unroll
    for (int kh = 0; kh < 3; ++kh) {
#pragma unroll
        for (int kw = 0; kw < 2; ++kw, ++rr) {
            const bf16* xp = a3 + ((size_t)(b * 26 + oh + kh) * 26 + (ow + kw)) * 32;
            const float* wp = wc4 + oc * 192 + rr * 32;
            short8 x0 = *(const short8*)(xp);
            short8 x1 = *(const short8*)(xp + 8);
            short8 x2 = *(const short8*)(xp + 16);
            short8 x3 = *(const short8*)(xp + 24);
#pragma unroll
            for (int j = 0; j < 8; ++j) {
                union { short s; unsigned short u; } u0{x0[j]}, u1{x1[j]}, u2{x2[j]}, u3{x3[j]};
                acc += wp[j]      * __bfloat162float(__hip_bfloat16_raw{u0.u});
                acc += wp[8 + j]  * __bfloat162float(__hip_bfloat16_raw{u1.u});
                acc += wp[16 + j] * __bfloat162float(__hip_bfloat16_raw{u2.u});
                acc += wp[24 + j] * __bfloat162float(__hip_bfloat16_raw{u3.u});
            }
        }
    }
    out[i] = acc;
}

// ---------------------------------------------------------------------------
extern "C" void kernel_launch(void* const* d_in, const int* in_sizes, int n_in,
                              void* d_out, int out_size, void* d_ws, size_t ws_size,
                              hipStream_t stream) {
    const float* x  = (const float*)d_in[0];
    const float* w1 = (const float*)d_in[1];
    const float* b1 = (const float*)d_in[2];
    const float* w2 = (const float*)d_in[3];
    const float* b2 = (const float*)d_in[4];
    const float* w3 = (const float*)d_in[5];
    const float* b3 = (const float*)d_in[6];
    const float* w4 = (const float*)d_in[7];
    const float* b4 = (const float*)d_in[8];
    float* out = (float*)d_out;

    char* ws = (char*)d_ws;
    size_t off = 0;
    auto alloc = [&](size_t bytes) {
        void* p = ws + off;
        off = (off + bytes + 255) & ~(size_t)255;
        return p;
    };
    bf16* a1 = (bf16*)alloc((size_t)32 * 111 * 111 * 128 * 2);  // NHWC
    bf16* a2 = (bf16*)alloc((size_t)32 * 54 * 54 * 64 * 2);     // NHWC
    bf16* a3 = (bf16*)alloc((size_t)32 * 26 * 26 * 32 * 2);     // NHWC
    bf16* w1m = (bf16*)alloc(2048 * 2);
    bf16* wAp2 = (bf16*)alloc(73728 * 2);
    bf16* wAp3 = (bf16*)alloc(18432 * 2);
    float* wc4 = (float*)alloc(1536 * 4);

    // binarize + pack all weights (one launch)
    binpack_kernel<<<dim3((95744 + 255) / 256), 256, 0, stream>>>(
        w1, w2, w3, w4, w1m, wAp2, wAp3, wc4);

    // conv1: x -> a1 [32,111,111,128]
    dim3 g1(7, 28, 32);
    conv1_kernel<<<g1, 256, 0, stream>>>(x, w1m, b1, a1);

    // conv2: a1 -> a2 [32,54,54,64]  (conv extent 108x108)
    dim3 g2(4, 7, 32);
    convmfma_kernel<128, 64, 111, 54><<<g2, 256, 0, stream>>>(a1, wAp2, b2, a2);

    // conv3: a2 -> a3 [32,26,26,32]  (conv extent 52x52)
    dim3 g3(2, 4, 32);
    convmfma_kernel<64, 32, 54, 26><<<g3, 256, 0, stream>>>(a2, wAp3, b3, a3);

    // conv4: a3 -> out [32,4800]
    conv4_kernel<<<dim3((32 * 4800 + 255) / 256), 256, 0, stream>>>(
        a3, wc4, b4, out);
}